// Round 6
// baseline (92.375 us; speedup 1.0000x reference)
//
#include <hip/hip_runtime.h>

// Problem: B=4, L=256, D=768, OUT=256
//   pj[b,j,o] = sum_d text[b,j,d] * weight[o, d]
//   pi[b,i,o] = sum_d text[b,i,d] * weight[o, 768+d]
//   out[b,i,j,o] = pi[b,i,o] + pj[b,j,o] + bias[o]
// out: 268 MB f32 -> write-BW bound (~40 us floor at fill's 6.8 TB/s).
//
// R6: gemv v4 — rows-in-registers, NO d-split, NO LDS reduce. 256 blocks
// (8 rows each): per-block WT read = 786KB -> total L2 traffic 201MB (was
// 402MB with 512 blocks; gemv was L2-BW-bound ~11.6us, not VALU-bound).
// Thread (o64, rg): 2 rows x 4 o, full d loop, 8 FMA per w4 load.
// bcast/transpose unchanged (R4 forms — proven best, reads don't matter).
//
// ws layout (floats):
//   WT  [768][512]      : WT[d][h*256+o] = weight[o][h*768+d]   (393216 floats)
//   P   [2][1024][256]  : P[0]=pj, P[1]=pi+bias                 (524288 floats)

#define DDIM 768
#define WT_FLOATS (768 * 512)
#define P_HALF (1024 * 256)

typedef float f4 __attribute__((ext_vector_type(4)));

// ---- tiled weight transpose: weight[256][1536] -> WT[768][512] ----
__global__ __launch_bounds__(256) void k_transpose(const float* __restrict__ W,
                                                   float* __restrict__ WT) {
    __shared__ float t[32][33];
    const int c0 = blockIdx.x * 32;
    const int o0 = blockIdx.y * 32;
    const int tx = threadIdx.x & 31, ty = threadIdx.x >> 5;
#pragma unroll
    for (int yy = ty; yy < 32; yy += 8)
        t[yy][tx] = W[(size_t)(o0 + yy) * 1536 + c0 + tx];
    __syncthreads();
#pragma unroll
    for (int yy = ty; yy < 32; yy += 8) {
        int c = c0 + yy;
        int h = (c >= 768) ? 1 : 0;
        int d = c - h * 768;
        WT[(size_t)d * 512 + h * 256 + o0 + tx] = t[tx][yy];
    }
}

// ---- P computation v4: 8 rows/block in registers, full-d per thread ----
// grid (128, 2), block 256. Thread: o64 = tid&63, rg = tid>>6 owns rows
// m0+rg*2, m0+rg*2+1 and o = o64*4..+4. No LDS, no reduction.
__global__ __launch_bounds__(256) void k_gemv(const float* __restrict__ text,
                                              const float* __restrict__ bias,
                                              const float* __restrict__ WT,
                                              float* __restrict__ P) {
    const int m0  = blockIdx.x * 8;
    const int h   = blockIdx.y;
    const int o64 = threadIdx.x & 63;
    const int rg  = __builtin_amdgcn_readfirstlane(threadIdx.x >> 6); // 0..3
    const int r0  = m0 + rg * 2;
    f4 a0 = (f4)0.0f, a1 = (f4)0.0f;
    const float* t0 = text + (size_t)r0 * DDIM;      // wave-uniform row pair
    const float* wt = WT + h * 256 + o64 * 4;
#pragma unroll 8
    for (int d = 0; d < DDIM; ++d) {
        f4 w4 = *(const f4*)(wt + (size_t)d * 512);   // coalesced, L1-shared x4 waves
        a0 += w4 * t0[d];                             // uniform -> s_load
        a1 += w4 * t0[DDIM + d];
    }
    if (h) {
        f4 b = *(const f4*)(bias + o64 * 4);          // fold bias into pi half
        a0 += b; a1 += b;
    }
    float* p = P + (size_t)h * P_HALF + (size_t)r0 * 256 + o64 * 4;
    *(f4*)p = a0;
    *(f4*)(p + 256) = a1;
}

// ---- broadcast add: out[r][j][o] = pi[r][o] + pj[b*256+j][o] ----
// grid 2048: r = bid>>1, half = bid&1 (j in [128*half, +128)). Plain stores,
// sequential 128KB per block. (R4 form — R5's reg-tile was equal.)
__global__ __launch_bounds__(256) void k_bcast(const float* __restrict__ P,
                                               float* __restrict__ out) {
    const int bid  = blockIdx.x;
    const int r    = bid >> 1;
    const int half = bid & 1;
    const int b    = r >> 8;
    const int o4 = (threadIdx.x & 63) * 4;
    const int jg = threadIdx.x >> 6;
    const f4 pi4 = *(const f4*)(P + (size_t)P_HALF + (size_t)r * 256 + o4);
    const float* pjb = P + (size_t)b * 65536;        // pj[b*256 + j][o]
    float* outr = out + (size_t)r * 65536;
    const int j0 = half * 128 + jg;
#pragma unroll 8
    for (int j = j0; j < j0 + 128 - jg; j += 4) {
        f4 pj4 = *(const f4*)(pjb + j * 256 + o4);   // L2-resident
        f4 v = pi4 + pj4;
        *(f4*)(outr + j * 256 + o4) = v;             // plain store, 1KB/wave
    }
}

extern "C" void kernel_launch(void* const* d_in, const int* in_sizes, int n_in,
                              void* d_out, int out_size, void* d_ws, size_t ws_size,
                              hipStream_t stream) {
    const float* text   = (const float*)d_in[0];   // [4][256][768]
    const float* weight = (const float*)d_in[1];   // [256][1536]
    const float* bias   = (const float*)d_in[2];   // [256]
    float* out = (float*)d_out;                    // [4][256][256][256]
    float* WT  = (float*)d_ws;                     // [768][512]
    float* P   = WT + WT_FLOATS;                   // [2][1024][256]

    k_transpose<<<dim3(48, 8), 256, 0, stream>>>(weight, WT);
    k_gemv<<<dim3(128, 2), 256, 0, stream>>>(text, bias, WT, P);
    k_bcast<<<2048, 256, 0, stream>>>(P, out);
}

// Round 7
// 70.160 us; speedup vs baseline: 1.3166x; 1.3166x over previous
//
#include <hip/hip_runtime.h>

// Problem: B=4, L=256, D=768, OUT=256
//   pj[b,j,o] = sum_d text[b,j,d] * weight[o, d]
//   pi[b,i,o] = sum_d text[b,i,d] * weight[o, 768+d]
//   out[b,i,j,o] = pi[b,i,o] + pj[b,j,o] + bias[o]
// out: 268 MB f32 -> write-BW bound (~40 us floor at fill's 6.8 TB/s).
//
// R7: gemv restored to R4 form (proven 69.8; R6's low-occupancy variant cost
// +22us). bcast v5: per-WAVE sequential 64KB streams (j step 1 within wave)
// instead of 1KB-chunks-at-4KB-stride — testing DRAM page locality as the
// last explanation for 5.0 vs fill's 6.9 TB/s.
//
// ws layout (floats):
//   WT  [768][512]      : WT[d][h*256+o] = weight[o][h*768+d]   (393216 floats)
//   P   [2][1024][256]  : P[0]=pj, P[1]=pi+bias                 (524288 floats)

#define DDIM 768
#define WT_FLOATS (768 * 512)
#define P_HALF (1024 * 256)

typedef float f4 __attribute__((ext_vector_type(4)));

// ---- tiled weight transpose: weight[256][1536] -> WT[768][512] ----
__global__ __launch_bounds__(256) void k_transpose(const float* __restrict__ W,
                                                   float* __restrict__ WT) {
    __shared__ float t[32][33];
    const int c0 = blockIdx.x * 32;
    const int o0 = blockIdx.y * 32;
    const int tx = threadIdx.x & 31, ty = threadIdx.x >> 5;
#pragma unroll
    for (int yy = ty; yy < 32; yy += 8)
        t[yy][tx] = W[(size_t)(o0 + yy) * 1536 + c0 + tx];
    __syncthreads();
#pragma unroll
    for (int yy = ty; yy < 32; yy += 8) {
        int c = c0 + yy;
        int h = (c >= 768) ? 1 : 0;
        int d = c - h * 768;
        WT[(size_t)d * 512 + h * 256 + o0 + tx] = t[tx][yy];
    }
}

// ---- P computation (R4 form): 4 rows/block, 4-way d-split, 1024 threads ----
// grid (256, 2) = 512 blocks, 2/CU, 32 waves/CU.
__global__ __launch_bounds__(1024) void k_gemv(const float* __restrict__ text,
                                               const float* __restrict__ bias,
                                               const float* __restrict__ WT,
                                               float* __restrict__ P) {
    __shared__ float red[4][4][256];   // 16 KB
    const int m0 = blockIdx.x * 4;
    const int h  = blockIdx.y;
    const int o  = threadIdx.x & 255;
    const int dg = __builtin_amdgcn_readfirstlane(threadIdx.x >> 8); // wave-uniform
    float acc[4];
#pragma unroll
    for (int r = 0; r < 4; ++r) acc[r] = 0.0f;
    const float* t0 = text + (size_t)m0 * DDIM + dg * 192;   // block+wave-uniform rows
    const float* wt = WT + (size_t)(dg * 192) * 512 + h * 256 + o;
#pragma unroll 8
    for (int d = 0; d < 192; ++d) {
        float w = wt[(size_t)d * 512];                       // coalesced across o, L2-hit
#pragma unroll
        for (int r = 0; r < 4; ++r)
            acc[r] = fmaf(t0[(size_t)r * DDIM + d], w, acc[r]);  // uniform -> scalar
    }
#pragma unroll
    for (int r = 0; r < 4; ++r) red[dg][r][o] = acc[r];
    __syncthreads();
    {
        int r = threadIdx.x >> 8, oo = threadIdx.x & 255;
        float s = red[0][r][oo] + red[1][r][oo] + red[2][r][oo] + red[3][r][oo];
        if (h) s += bias[oo];                                // fold bias into pi half
        P[(size_t)h * P_HALF + (size_t)(m0 + r) * 256 + oo] = s;
    }
}

// ---- broadcast add v5: per-wave sequential 64KB streams ----
// grid 1024 (r = b*256+i), 256 threads = 4 waves. Wave w owns j in
// [w*64, w*64+64) stepping by 1 -> each wave stores 64 x 1KB CONSECUTIVE.
__global__ __launch_bounds__(256) void k_bcast(const float* __restrict__ P,
                                               float* __restrict__ out) {
    const int r  = blockIdx.x;
    const int b  = r >> 8;
    const int o4 = (threadIdx.x & 63) * 4;
    const int w  = threadIdx.x >> 6;                 // wave id 0..3
    const f4 pi4 = *(const f4*)(P + (size_t)P_HALF + (size_t)r * 256 + o4);
    const float* pjb = P + (size_t)b * 65536 + o4;   // pj[b*256 + j][o4]
    float* outr = out + (size_t)r * 65536 + o4;
    const int j0 = w * 64;
#pragma unroll 8
    for (int j = j0; j < j0 + 64; ++j) {
        f4 pj4 = *(const f4*)(pjb + (size_t)j * 256);    // L2-resident
        f4 v = pi4 + pj4;
        *(f4*)(outr + (size_t)j * 256) = v;              // sequential 1KB/wave/iter
    }
}

extern "C" void kernel_launch(void* const* d_in, const int* in_sizes, int n_in,
                              void* d_out, int out_size, void* d_ws, size_t ws_size,
                              hipStream_t stream) {
    const float* text   = (const float*)d_in[0];   // [4][256][768]
    const float* weight = (const float*)d_in[1];   // [256][1536]
    const float* bias   = (const float*)d_in[2];   // [256]
    float* out = (float*)d_out;                    // [4][256][256][256]
    float* WT  = (float*)d_ws;                     // [768][512]
    float* P   = WT + WT_FLOATS;                   // [2][1024][256]

    k_transpose<<<dim3(48, 8), 256, 0, stream>>>(weight, WT);
    k_gemv<<<dim3(256, 2), 1024, 0, stream>>>(text, bias, WT, P);
    k_bcast<<<1024, 256, 0, stream>>>(P, out);
}